// Round 3
// baseline (231.367 us; speedup 1.0000x reference)
//
#include <hip/hip_runtime.h>

// SubManifold gather: out[b,w,i,j] = x[b, idx[w,i], idx[w,j]]
// idx[w=wr*10+wc, i=a*12+b] = 192*wr + 4*wc + 48*a + b
// Static config: D=48, N=2304, K=12 (kk=144), S=4, 10x10=100 windows, BS=8.
// Output: [8,100,144,144] fp32; one thread per output float4.
// 4,147,200 float4 = 16200 blocks x 256 threads (exact, no bounds check).
//
// R3: same as R2 but with clang-native float4 (ext_vector_type) so
// __builtin_nontemporal_store compiles. XCD-locality swizzle: 16200 blocks
// / 8 XCDs = 2025 contiguous blocks per XCD = exactly one batch b (100
// windows in sliding order). Cross-window 128B-line reuse (9x overlap)
// hits the XCD-local 4MB L2 (live set ~3.2MB) instead of L3.
// NT stores keep the write-once 66MB output from evicting x lines in L2.

typedef float vf4 __attribute__((ext_vector_type(4)));

namespace {
constexpr int NTOK = 2304;   // N = 48*48
constexpr int NW   = 100;    // windows
constexpr int KK   = 144;    // k*k
constexpr int QPR  = 36;     // float4 per output row (144/4)
constexpr int TOTAL_F4 = 8 * NW * KK * QPR;   // 4,147,200
constexpr int NBLK = TOTAL_F4 / 256;          // 16200
constexpr int BLK_PER_XCD = NBLK / 8;         // 2025 (exact)
}

__global__ __launch_bounds__(256) void submanifold_gather(
    const float* __restrict__ x, vf4* __restrict__ out) {
    // Default dispatch: XCD = blockIdx.x % 8. Remap so XCD k owns the
    // contiguous work range [k*2025, (k+1)*2025) = batch k.
    int bx = blockIdx.x;
    int sb = (bx & 7) * BLK_PER_XCD + (bx >> 3);
    int t  = sb * 256 + (int)threadIdx.x;

    int q   = t % QPR;          // which float4 within a 144-long out row
    int rid = t / QPR;          // (b, w, i)
    int i   = rid % KK;
    int bw  = rid / KK;
    int w   = bw % NW;
    int b   = bw / NW;

    int wr = w / 10;
    int wc = w - wr * 10;
    int base = 192 * wr + 4 * wc;          // window's flat token base

    int ai = i / 12;
    int bi = i - ai * 12;
    int r  = base + 48 * ai + bi;          // source row (flat token idx)

    int aj  = q / 3;
    int bj4 = (q - aj * 3) * 4;
    int c   = base + 48 * aj + bj4;        // source col start (mult of 4)

    const vf4* src = reinterpret_cast<const vf4*>(
        x + (size_t)b * NTOK * NTOK + (size_t)r * NTOK + c);
    vf4 v = *src;
    __builtin_nontemporal_store(v, &out[t]);
}

extern "C" void kernel_launch(void* const* d_in, const int* in_sizes, int n_in,
                              void* d_out, int out_size, void* d_ws, size_t ws_size,
                              hipStream_t stream) {
    const float* x = (const float*)d_in[0];
    vf4* out = (vf4*)d_out;
    submanifold_gather<<<NBLK, 256, 0, stream>>>(x, out);
}